// Round 7
// baseline (3312.380 us; speedup 1.0000x reference)
//
#include <hip/hip_runtime.h>
#include <hip/hip_bf16.h>

#define N_IN    262144
#define N_OUT   393216
#define M_PAIRS 262144
#define KK      27
#define CIN     32
#define COUT    64
#define BN_EPS  1e-5f

#define TOTAL_E      (KK * M_PAIRS)          // 7,077,888
#define ROWS_PER_BIN 128
#define NR           (N_OUT / ROWS_PER_BIN)  // 3072
#define NBINS        (NR * KK)               // 82944 = 81 * 1024
#define ACCW         65                      // padded acc row stride
#define ACCR         129                     // 128 real rows + 1 trash row
#define RECCAP       (TOTAL_E + 15 * NBINS + 80)   // padded records + overread pad
#define DUMMY_REC    (128u << 18)            // in_i=0, lo=128 (trash row)

typedef unsigned int u32;
typedef float f32x4 __attribute__((ext_vector_type(4)));
typedef short s16x8 __attribute__((ext_vector_type(8)));

static __device__ __forceinline__ short f2bf(float f) {
    __hip_bfloat16 h = __float2bfloat16(f);
    return *reinterpret_cast<short*>(&h);
}

// ---------------- W convert: f32 [K][CIN][COUT] -> bf16 [K][COUT][CIN] ------
__global__ __launch_bounds__(256) void w_convert(
    const float* __restrict__ W, short* __restrict__ Wt)
{
    const int t = blockIdx.x * 256 + threadIdx.x;
    if (t >= KK * COUT * CIN) return;
    const int k    = t / (COUT * CIN);
    const int rem  = t % (COUT * CIN);
    const int co   = rem / CIN;
    const int ci   = rem % CIN;
    Wt[t] = f2bf(W[k * CIN * COUT + ci * COUT + co]);
}

// ---------------- data convert: f32 [N_IN][CIN] -> bf16 rows (64 B/row) ----
__global__ __launch_bounds__(256) void data_convert(
    const f32x4* __restrict__ in, s16x8* __restrict__ outp)
{
    const int t = blockIdx.x * 256 + threadIdx.x;   // one per 8 floats
    if (t >= N_IN * CIN / 8) return;
    const f32x4 x0 = in[2 * t];
    const f32x4 x1 = in[2 * t + 1];
    s16x8 o;
    o[0] = f2bf(x0[0]); o[1] = f2bf(x0[1]); o[2] = f2bf(x0[2]); o[3] = f2bf(x0[3]);
    o[4] = f2bf(x1[0]); o[5] = f2bf(x1[1]); o[6] = f2bf(x1[2]); o[7] = f2bf(x1[3]);
    outp[t] = o;
}

// ---------------- Phase A1: histogram over (range, k) bins ----------------
__global__ __launch_bounds__(256) void bin_count(
    const int4* __restrict__ out_idx4, u32* __restrict__ cnt)
{
    const int stride = gridDim.x * 256;
    for (int e4 = blockIdx.x * 256 + threadIdx.x; e4 < TOTAL_E / 4; e4 += stride) {
        const int k = e4 >> 16;              // e = 4*e4 ; k = e >> 18
        const int4 v = out_idx4[e4];
        atomicAdd(&cnt[(v.x >> 7) * KK + k], 1u);
        atomicAdd(&cnt[(v.y >> 7) * KK + k], 1u);
        atomicAdd(&cnt[(v.z >> 7) * KK + k], 1u);
        atomicAdd(&cnt[(v.w >> 7) * KK + k], 1u);
    }
}

// ---------------- Phase A2: hierarchical scan over PADDED counts -----------
// padded length = (len + 15) & ~15 so every segment is a whole number of
// 16-record sub-batches -> branch-free accumulate loop.
__global__ __launch_bounds__(1024) void scan_part(
    const u32* __restrict__ cnt, u32* __restrict__ partial)
{
    __shared__ u32 sh[1024];
    sh[threadIdx.x] = (cnt[blockIdx.x * 1024 + threadIdx.x] + 15u) & ~15u;
    __syncthreads();
    for (int d = 512; d > 0; d >>= 1) {
        if (threadIdx.x < d) sh[threadIdx.x] += sh[threadIdx.x + d];
        __syncthreads();
    }
    if (threadIdx.x == 0) partial[blockIdx.x] = sh[0];
}

__global__ void scan_small(u32* __restrict__ partial)  // 1 thread: 81 entries
{
    u32 run = 0;
    for (int i = 0; i < NBINS / 1024; ++i) {
        const u32 v = partial[i];
        partial[i] = run;
        run += v;
    }
}

__global__ __launch_bounds__(1024) void scan_final(
    u32* __restrict__ cnt, u32* __restrict__ off, const u32* __restrict__ partial)
{
    __shared__ u32 sh[1024];
    const int t = threadIdx.x;
    const int i = blockIdx.x * 1024 + t;
    const u32 v = (cnt[i] + 15u) & ~15u;
    sh[t] = v;
    __syncthreads();
    for (int d = 1; d < 1024; d <<= 1) {
        const u32 add = (t >= d) ? sh[t - d] : 0u;
        __syncthreads();
        sh[t] += add;
        __syncthreads();
    }
    const u32 excl = sh[t] - v + partial[blockIdx.x];
    off[i] = excl;
    cnt[i] = excl;                 // cursor for A3 (real records fill from here)
    if (i == NBINS - 1) off[NBINS] = excl + v;   // padded total
}

// ---------------- Phase A3: scatter packed records into segments ----------
// record = in_i (18b) | local_out (8b field, real values 0..127) << 18
__global__ __launch_bounds__(256) void bin_scatter(
    const int4* __restrict__ in_idx4, const int4* __restrict__ out_idx4,
    u32* __restrict__ cursor, u32* __restrict__ rec)
{
    const int stride = gridDim.x * 256;
    for (int e4 = blockIdx.x * 256 + threadIdx.x; e4 < TOTAL_E / 4; e4 += stride) {
        const int k  = e4 >> 16;
        const int4 oi = out_idx4[e4];
        const int4 ii = in_idx4[e4];
        {
            const u32 pos = atomicAdd(&cursor[(oi.x >> 7) * KK + k], 1u);
            rec[pos] = (u32)ii.x | ((u32)(oi.x & 127) << 18);
        }
        {
            const u32 pos = atomicAdd(&cursor[(oi.y >> 7) * KK + k], 1u);
            rec[pos] = (u32)ii.y | ((u32)(oi.y & 127) << 18);
        }
        {
            const u32 pos = atomicAdd(&cursor[(oi.z >> 7) * KK + k], 1u);
            rec[pos] = (u32)ii.z | ((u32)(oi.z & 127) << 18);
        }
        {
            const u32 pos = atomicAdd(&cursor[(oi.w >> 7) * KK + k], 1u);
            rec[pos] = (u32)ii.w | ((u32)(oi.w & 127) << 18);
        }
    }
}

// ---------------- Phase A4: fill pad slots with dummy records --------------
__global__ __launch_bounds__(256) void fill_pad(
    const u32* __restrict__ cursor,   // real end of each segment
    const u32* __restrict__ off,      // padded offsets
    u32* __restrict__ rec)
{
    const int b = blockIdx.x * 256 + threadIdx.x;
    if (b >= NBINS) return;
    const u32 e0 = cursor[b];
    const u32 e1 = off[b + 1];
    for (u32 p = e0; p < e1; ++p) rec[p] = DUMMY_REC;
}

// ---------------- Phase B: branch-free pipelined MFMA accumulate -----------
// Swapped operands (verified r6): D col = record = lane&15, lane-local scatter.
// 3-deep gather pipeline, unconditional inner loop, dummies land in trash row.
__global__ __launch_bounds__(256, 3) void range_accum(
    const short* __restrict__ dbf,    // [N_IN, CIN] bf16 bits
    const short* __restrict__ Wt,     // [K, COUT, CIN] bf16 bits
    const u32*  __restrict__ off,     // [NBINS+1] padded offsets
    const u32*  __restrict__ rec,     // [RECCAP]
    float*      __restrict__ out,     // [N_OUT, COUT]
    float*      __restrict__ stats)   // [128]
{
    __shared__ float acc[ACCR * ACCW];          // 33540 B (incl. trash row 128)
    __shared__ float sred[512];

    const int r    = blockIdx.x;
    const int tid  = threadIdx.x;
    const int wave = tid >> 6;       // 0..3
    const int lane = tid & 63;
    const int jrow = lane & 15;      // record slot within sub-batch / D col
    const int kq   = lane >> 4;      // cin-chunk / D row group

    for (int i = tid; i < ACCR * ACCW; i += 256) acc[i] = 0.0f;
    __syncthreads();

    for (int k = wave; k < KK; k += 4) {
        const short* wb = Wt + (k * COUT + jrow) * CIN + kq * 8;
        const s16x8 w0 = *(const s16x8*)(wb + 0 * 16 * CIN);
        const s16x8 w1 = *(const s16x8*)(wb + 1 * 16 * CIN);
        const s16x8 w2 = *(const s16x8*)(wb + 2 * 16 * CIN);
        const s16x8 w3 = *(const s16x8*)(wb + 3 * 16 * CIN);

        const u32 begin = off[r * KK + k];
        const u32 nsb   = (off[r * KK + k + 1] - begin) >> 4;   // exact

        u32 p = begin + (u32)jrow;
        // pipeline prologue (overreads are valid slots / masked rows)
        u32 rc0 = rec[p];
        u32 rc1 = rec[p + 16];
        u32 rc2 = rec[p + 32];
        u32 rc3 = rec[p + 48];
        s16x8 a0 = *(const s16x8*)(dbf + (size_t)(rc0 & 0x3FFFFu) * CIN + kq * 8);
        s16x8 a1 = *(const s16x8*)(dbf + (size_t)(rc1 & 0x3FFFFu) * CIN + kq * 8);
        s16x8 a2 = *(const s16x8*)(dbf + (size_t)(rc2 & 0x3FFFFu) * CIN + kq * 8);

        for (u32 s = 0; s < nsb; ++s) {
            const u32   rc4 = rec[p + 64];
            const s16x8 a3  = *(const s16x8*)(dbf + (size_t)(rc3 & 0x3FFFFu) * CIN + kq * 8);
            __builtin_amdgcn_sched_barrier(0);

            {
                const f32x4 z = {0.f, 0.f, 0.f, 0.f};
                const f32x4 d0 = __builtin_amdgcn_mfma_f32_16x16x32_bf16(w0, a0, z, 0, 0, 0);
                const f32x4 d1 = __builtin_amdgcn_mfma_f32_16x16x32_bf16(w1, a0, z, 0, 0, 0);
                const f32x4 d2 = __builtin_amdgcn_mfma_f32_16x16x32_bf16(w2, a0, z, 0, 0, 0);
                const f32x4 d3 = __builtin_amdgcn_mfma_f32_16x16x32_bf16(w3, a0, z, 0, 0, 0);
                const int lo = (int)((rc0 >> 18) & 255u);    // 0..127 real, 128 trash
                float* ap = acc + lo * ACCW + kq * 4;
                #pragma unroll
                for (int g = 0; g < 4; ++g) {
                    atomicAdd(ap + g,      d0[g]);
                    atomicAdd(ap + 16 + g, d1[g]);
                    atomicAdd(ap + 32 + g, d2[g]);
                    atomicAdd(ap + 48 + g, d3[g]);
                }
            }
            __builtin_amdgcn_sched_barrier(0);

            rc0 = rc1; rc1 = rc2; rc2 = rc3; rc3 = rc4;
            a0 = a1;   a1 = a2;   a2 = a3;
            p += 16;
        }
    }
    __syncthreads();

    // fused BN partial stats over real rows 0..127
    {
        const int c = tid & 63;
        float s = 0.0f, sq = 0.0f;
        for (int row = tid >> 6; row < ROWS_PER_BIN; row += 4) {
            const float x = acc[row * ACCW + c];
            s += x; sq += x * x;
        }
        sred[tid]       = s;
        sred[256 + tid] = sq;
        __syncthreads();
        if (tid < 64) {
            atomicAdd(&stats[tid],      sred[tid] + sred[tid + 64] + sred[tid + 128] + sred[tid + 192]);
            atomicAdd(&stats[64 + tid], sred[256 + tid] + sred[320 + tid] + sred[384 + tid] + sred[448 + tid]);
        }
    }

    // coalesced store of the 128x64 block (strip ACCW pad, skip trash row)
    for (int i = tid; i < ROWS_PER_BIN * COUT; i += 256) {
        const int row = i >> 6;
        const int c   = i & 63;
        out[(size_t)r * (ROWS_PER_BIN * COUT) + i] = acc[row * ACCW + c];
    }
}

// ---------------- f32-data fallback (padded/dummy-aware) -------------------
__global__ __launch_bounds__(256) void range_accum_f32(
    const float* __restrict__ df,
    const short* __restrict__ Wt,
    const u32*  __restrict__ off,
    const u32*  __restrict__ rec,
    float*      __restrict__ out,
    float*      __restrict__ stats)
{
    __shared__ float acc[ACCR * ACCW];
    __shared__ float sred[512];
    const int r    = blockIdx.x;
    const int tid  = threadIdx.x;
    const int wave = tid >> 6;
    const int lane = tid & 63;
    const int jrow = lane & 15;
    const int kq   = lane >> 4;

    for (int i = tid; i < ACCR * ACCW; i += 256) acc[i] = 0.0f;
    __syncthreads();

    for (int k = wave; k < KK; k += 4) {
        const short* wb = Wt + (k * COUT + jrow) * CIN + kq * 8;
        const s16x8 w0 = *(const s16x8*)(wb + 0 * 16 * CIN);
        const s16x8 w1 = *(const s16x8*)(wb + 1 * 16 * CIN);
        const s16x8 w2 = *(const s16x8*)(wb + 2 * 16 * CIN);
        const s16x8 w3 = *(const s16x8*)(wb + 3 * 16 * CIN);
        const u32 begin = off[r * KK + k];
        const u32 end   = off[r * KK + k + 1];    // padded: multiple of 16
        for (u32 base = begin; base < end; base += 16) {
            const u32 rc = rec[base + (u32)jrow];
            const float* dp = df + (size_t)(rc & 0x3FFFFu) * CIN + kq * 8;
            const f32x4 x0 = *(const f32x4*)dp;
            const f32x4 x1 = *(const f32x4*)(dp + 4);
            s16x8 a;
            a[0]=f2bf(x0[0]); a[1]=f2bf(x0[1]); a[2]=f2bf(x0[2]); a[3]=f2bf(x0[3]);
            a[4]=f2bf(x1[0]); a[5]=f2bf(x1[1]); a[6]=f2bf(x1[2]); a[7]=f2bf(x1[3]);
            const f32x4 z = {0.f,0.f,0.f,0.f};
            const f32x4 d0 = __builtin_amdgcn_mfma_f32_16x16x32_bf16(w0, a, z, 0, 0, 0);
            const f32x4 d1 = __builtin_amdgcn_mfma_f32_16x16x32_bf16(w1, a, z, 0, 0, 0);
            const f32x4 d2 = __builtin_amdgcn_mfma_f32_16x16x32_bf16(w2, a, z, 0, 0, 0);
            const f32x4 d3 = __builtin_amdgcn_mfma_f32_16x16x32_bf16(w3, a, z, 0, 0, 0);
            const int lo = (int)((rc >> 18) & 255u);
            float* ap = acc + lo * ACCW + kq * 4;
            #pragma unroll
            for (int g = 0; g < 4; ++g) {
                atomicAdd(ap + g,      d0[g]);
                atomicAdd(ap + 16 + g, d1[g]);
                atomicAdd(ap + 32 + g, d2[g]);
                atomicAdd(ap + 48 + g, d3[g]);
            }
        }
    }
    __syncthreads();
    {
        const int c = tid & 63;
        float s = 0.0f, sq = 0.0f;
        for (int row = tid >> 6; row < ROWS_PER_BIN; row += 4) {
            const float x = acc[row * ACCW + c];
            s += x; sq += x * x;
        }
        sred[tid] = s; sred[256 + tid] = sq;
        __syncthreads();
        if (tid < 64) {
            atomicAdd(&stats[tid],      sred[tid] + sred[tid+64] + sred[tid+128] + sred[tid+192]);
            atomicAdd(&stats[64+tid],   sred[256+tid] + sred[320+tid] + sred[384+tid] + sred[448+tid]);
        }
    }
    for (int i = tid; i < ROWS_PER_BIN * COUT; i += 256) {
        const int row = i >> 6;
        const int c   = i & 63;
        out[(size_t)r * (ROWS_PER_BIN * COUT) + i] = acc[row * ACCW + c];
    }
}

// ---------------- BN normalize (in place) ----------------
__global__ __launch_bounds__(256) void bn_norm(
    float* __restrict__ out, const float* __restrict__ stats,
    const float* __restrict__ gamma, const float* __restrict__ beta)
{
    __shared__ float scale[COUT], bias[COUT];
    if (threadIdx.x < COUT) {
        const int c = threadIdx.x;
        const float invN = 1.0f / (float)N_OUT;
        const float mean = stats[c] * invN;
        const float var  = stats[64 + c] * invN - mean * mean;
        const float inv  = rsqrtf(var + BN_EPS);
        const float g    = gamma[c];
        scale[c] = inv * g;
        bias[c]  = beta[c] - mean * inv * g;
    }
    __syncthreads();

    const int tid    = blockIdx.x * blockDim.x + threadIdx.x;
    const int stride = gridDim.x * blockDim.x;
    const int total4 = N_OUT * COUT / 4;
    float4* o4 = (float4*)out;
    for (int i = tid; i < total4; i += stride) {
        float4 v = o4[i];
        const int c0 = (i * 4) & 63;
        v.x = v.x * scale[c0 + 0] + bias[c0 + 0];
        v.y = v.y * scale[c0 + 1] + bias[c0 + 1];
        v.z = v.z * scale[c0 + 2] + bias[c0 + 2];
        v.w = v.w * scale[c0 + 3] + bias[c0 + 3];
        o4[i] = v;
    }
}

// ---------------- Fallback (round-1 path) if workspace too small ----------
__global__ __launch_bounds__(256) void conv_scatter_fb(
    const float* __restrict__ data, const float* __restrict__ W,
    const int* __restrict__ in_idx, const int* __restrict__ out_idx,
    float* __restrict__ out)
{
    __shared__ float Wlds[CIN * COUT];
    const int k   = blockIdx.x / 256;
    const int blk = blockIdx.x % 256;
    for (int i = threadIdx.x; i < CIN * COUT; i += 256)
        Wlds[i] = W[k * CIN * COUT + i];
    __syncthreads();
    const int wave = threadIdx.x >> 6;
    const int lane = threadIdx.x & 63;
    const int base = k * M_PAIRS + blk * 1024 + wave * 256;
    for (int p = 0; p < 256; ++p) {
        const int in_i  = in_idx[base + p];
        const int out_i = out_idx[base + p];
        const float val = data[in_i * CIN + (lane & 31)];
        float a = 0.0f;
        #pragma unroll
        for (int c = 0; c < CIN; ++c)
            a = fmaf(__shfl(val, c, 64), Wlds[c * COUT + lane], a);
        atomicAdd(&out[out_i * COUT + lane], a);
    }
}

__global__ __launch_bounds__(256) void bn_stats_fb(
    const float* __restrict__ out, float* __restrict__ stats)
{
    const int tid    = blockIdx.x * 256 + threadIdx.x;
    const int stride = gridDim.x * 256;
    float s = 0.0f, sq = 0.0f;
    for (int i = tid; i < N_OUT * COUT; i += stride) {
        const float x = out[i]; s += x; sq += x * x;
    }
    __shared__ float ls[256], lsq[256];
    ls[threadIdx.x] = s; lsq[threadIdx.x] = sq;
    __syncthreads();
    if (threadIdx.x < 64) {
        const int c = threadIdx.x;
        atomicAdd(&stats[c],      ls[c] + ls[c+64] + ls[c+128] + ls[c+192]);
        atomicAdd(&stats[64 + c], lsq[c] + lsq[c+64] + lsq[c+128] + lsq[c+192]);
    }
}

extern "C" void kernel_launch(void* const* d_in, const int* in_sizes, int n_in,
                              void* d_out, int out_size, void* d_ws, size_t ws_size,
                              hipStream_t stream) {
    const float* data    = (const float*)d_in[0];
    const float* W       = (const float*)d_in[1];
    const float* gamma   = (const float*)d_in[2];
    const float* beta    = (const float*)d_in[3];
    const int*   in_idx  = (const int*)d_in[4];
    const int*   out_idx = (const int*)d_in[5];
    float* out = (float*)d_out;

    // workspace layout (u32 units; every section 16B-aligned)
    u32* cnt     = (u32*)d_ws;                       // NBINS
    u32* off     = cnt + NBINS;                      // NBINS+4
    u32* rec     = off + NBINS + 4;                  // RECCAP
    u32* partial = rec + RECCAP;                     // 128
    short* Wt    = (short*)(partial + 128);          // KK*COUT*CIN shorts
    float* stats = (float*)(Wt + KK * COUT * CIN);   // 128
    short* dataBF = (short*)(stats + 128);           // N_IN*CIN shorts (16.8 MB)

    const size_t base_needed =
        (size_t)(NBINS + NBINS + 4 + RECCAP + 128 + KK * COUT * CIN / 2 + 128) * 4;
    const size_t bf_needed = base_needed + (size_t)N_IN * CIN * 2;

    if (ws_size >= base_needed) {
        hipMemsetAsync(cnt, 0, (size_t)NBINS * sizeof(u32), stream);
        hipMemsetAsync(stats, 0, 128 * sizeof(float), stream);

        w_convert<<<(KK * COUT * CIN + 255) / 256, 256, 0, stream>>>(W, Wt);
        bin_count<<<2048, 256, 0, stream>>>((const int4*)out_idx, cnt);
        scan_part<<<NBINS / 1024, 1024, 0, stream>>>(cnt, partial);
        scan_small<<<1, 1, 0, stream>>>(partial);
        scan_final<<<NBINS / 1024, 1024, 0, stream>>>(cnt, off, partial);
        bin_scatter<<<2048, 256, 0, stream>>>((const int4*)in_idx, (const int4*)out_idx, cnt, rec);
        fill_pad<<<(NBINS + 255) / 256, 256, 0, stream>>>(cnt, off, rec);

        if (ws_size >= bf_needed) {
            data_convert<<<(N_IN * CIN / 8 + 255) / 256, 256, 0, stream>>>(
                (const f32x4*)data, (s16x8*)dataBF);
            range_accum<<<NR, 256, 0, stream>>>(dataBF, Wt, off, rec, out, stats);
        } else {
            range_accum_f32<<<NR, 256, 0, stream>>>(data, Wt, off, rec, out, stats);
        }
        bn_norm<<<2048, 256, 0, stream>>>(out, stats, gamma, beta);
    } else {
        float* stats_fb = (float*)d_ws;
        hipMemsetAsync(d_out, 0, (size_t)N_OUT * COUT * sizeof(float), stream);
        hipMemsetAsync(stats_fb, 0, 128 * sizeof(float), stream);
        conv_scatter_fb<<<KK * 256, 256, 0, stream>>>(data, W, in_idx, out_idx, out);
        bn_stats_fb<<<1024, 256, 0, stream>>>(out, stats_fb);
        bn_norm<<<2048, 256, 0, stream>>>(out, stats_fb, gamma, beta);
    }
}

// Round 9
// 3226.695 us; speedup vs baseline: 1.0266x; 1.0266x over previous
//
#include <hip/hip_runtime.h>
#include <hip/hip_bf16.h>

#define N_IN    262144
#define N_OUT   393216
#define M_PAIRS 262144
#define KK      27
#define CIN     32
#define COUT    64
#define BN_EPS  1e-5f

#define BPK 256                                   // blocks per kernel-offset k
#define CONV_BLOCK 256

typedef unsigned int u32;

static __device__ __forceinline__ u32 pack_bf2(float lo, float hi) {
    __hip_bfloat16 a = __float2bfloat16(lo);
    __hip_bfloat16 b = __float2bfloat16(hi);
    return (u32)*reinterpret_cast<unsigned short*>(&a)
         | ((u32)*reinterpret_cast<unsigned short*>(&b) << 16);
}

static __device__ __forceinline__ float bfbits2f(u32 bits16) {
    return __uint_as_float(bits16 << 16);
}

// packed bf16x2 atomic add (gfx950 global_atomic_pk_add_bf16), fire-and-forget
static __device__ __forceinline__ void atomic_pk_add_bf16(u32* addr, u32 packed) {
    asm volatile("global_atomic_pk_add_bf16 %0, %1, off"
                 :: "v"((void*)addr), "v"(packed)
                 : "memory");
}

// ---------------- conv: rulebook gather -> dot -> packed-bf16 atomic scatter
// r1's verified skeleton; only the accumulation target changed (f32->pk bf16).
__global__ __launch_bounds__(CONV_BLOCK) void conv_scatter_pk(
    const float* __restrict__ data,      // [N_IN, CIN]
    const float* __restrict__ W,         // [K, CIN, COUT]
    const int*   __restrict__ in_idx,    // [K, M]
    const int*   __restrict__ out_idx,   // [K, M]
    u32*         __restrict__ outbf)     // [N_OUT*32] bf16 pairs (pre-zeroed)
{
    __shared__ float Wlds[CIN * COUT];   // 8 KB: W_k staged per block
    const int k   = blockIdx.x / BPK;
    const int blk = blockIdx.x % BPK;

    for (int i = threadIdx.x; i < CIN * COUT; i += CONV_BLOCK)
        Wlds[i] = W[k * CIN * COUT + i];
    __syncthreads();

    const int wave = threadIdx.x >> 6;
    const int lane = threadIdx.x & 63;
    const int base = k * M_PAIRS + blk * 1024 + wave * 256;

    for (int p = 0; p < 256; ++p) {
        const int in_i  = in_idx[base + p];
        const int out_i = out_idx[base + p];
        // lanes 0..31 fetch the 128B row; lanes 32..63 duplicate (same lines)
        const float val = data[in_i * CIN + (lane & 31)];
        float acc = 0.0f;
        #pragma unroll
        for (int c = 0; c < CIN; ++c) {
            const float rowv = __shfl(val, c, 64);   // broadcast row elem c
            acc = fmaf(rowv, Wlds[c * COUT + lane], acc);
        }
        // pair up couts (2c, 2c+1) across even/odd lanes -> one 4B pk atomic
        const float accN = __shfl(acc, lane ^ 1, 64);
        if (!(lane & 1)) {
            atomic_pk_add_bf16(&outbf[out_i * 32 + (lane >> 1)],
                               pack_bf2(acc, accN));
        }
    }
}

// ---------------- BN stats over the bf16 buffer ----------------
__global__ __launch_bounds__(256) void bn_stats_bf(
    const u32* __restrict__ outbf, float* __restrict__ stats /* [128] */)
{
    __shared__ float s_[256];     // [0..127] per-cout sum, [128..255] sumsq
    s_[threadIdx.x] = 0.0f;
    __syncthreads();

    const int tid    = blockIdx.x * 256 + threadIdx.x;
    const int stride = gridDim.x * 256;          // multiple of 32
    const int j      = threadIdx.x & 31;         // fixed pair-column
    float s0 = 0.f, q0 = 0.f, s1 = 0.f, q1 = 0.f;
    for (int i = tid; i < N_OUT * 32; i += stride) {
        const u32 v = outbf[i];
        const float x0 = bfbits2f(v & 0xFFFFu);
        const float x1 = bfbits2f(v >> 16);
        s0 += x0; q0 += x0 * x0;
        s1 += x1; q1 += x1 * x1;
    }
    atomicAdd(&s_[2 * j],           s0);
    atomicAdd(&s_[2 * j + 1],       s1);
    atomicAdd(&s_[128 + 2 * j],     q0);
    atomicAdd(&s_[128 + 2 * j + 1], q1);
    __syncthreads();
    if (threadIdx.x < 64) {
        atomicAdd(&stats[threadIdx.x],      s_[threadIdx.x]);
        atomicAdd(&stats[64 + threadIdx.x], s_[128 + threadIdx.x]);
    }
}

// ---------------- BN normalize: bf16 buffer -> f32 out ----------------
__global__ __launch_bounds__(256) void bn_norm_bf(
    const u32* __restrict__ outbf, const float* __restrict__ stats,
    const float* __restrict__ gamma, const float* __restrict__ beta,
    float* __restrict__ out)
{
    __shared__ float scale[COUT], bias[COUT];
    if (threadIdx.x < COUT) {
        const int c = threadIdx.x;
        const float invN = 1.0f / (float)N_OUT;
        const float mean = stats[c] * invN;
        const float var  = stats[64 + c] * invN - mean * mean;
        const float inv  = rsqrtf(var + BN_EPS);
        const float g    = gamma[c];
        scale[c] = inv * g;
        bias[c]  = beta[c] - mean * inv * g;
    }
    __syncthreads();

    const int tid    = blockIdx.x * blockDim.x + threadIdx.x;
    const int stride = gridDim.x * blockDim.x;
    float2* o2 = (float2*)out;
    for (int i = tid; i < N_OUT * 32; i += stride) {
        const u32 v = outbf[i];
        const int c0 = (i & 31) * 2;             // cout pair
        float2 r;
        r.x = bfbits2f(v & 0xFFFFu) * scale[c0]     + bias[c0];
        r.y = bfbits2f(v >> 16)     * scale[c0 + 1] + bias[c0 + 1];
        o2[i] = r;
    }
}

// ================= r1 fallback (f32 atomics straight to out) ===============
__global__ __launch_bounds__(CONV_BLOCK) void conv_scatter_fb(
    const float* __restrict__ data, const float* __restrict__ W,
    const int* __restrict__ in_idx, const int* __restrict__ out_idx,
    float* __restrict__ out)
{
    __shared__ float Wlds[CIN * COUT];
    const int k   = blockIdx.x / BPK;
    const int blk = blockIdx.x % BPK;
    for (int i = threadIdx.x; i < CIN * COUT; i += CONV_BLOCK)
        Wlds[i] = W[k * CIN * COUT + i];
    __syncthreads();
    const int wave = threadIdx.x >> 6;
    const int lane = threadIdx.x & 63;
    const int base = k * M_PAIRS + blk * 1024 + wave * 256;
    for (int p = 0; p < 256; ++p) {
        const int in_i  = in_idx[base + p];
        const int out_i = out_idx[base + p];
        const float val = data[in_i * CIN + (lane & 31)];
        float acc = 0.0f;
        #pragma unroll
        for (int c = 0; c < CIN; ++c)
            acc = fmaf(__shfl(val, c, 64), Wlds[c * COUT + lane], acc);
        atomicAdd(&out[out_i * COUT + lane], acc);
    }
}

__global__ __launch_bounds__(256) void bn_stats_fb(
    const float* __restrict__ out, float* __restrict__ stats)
{
    const int tid    = blockIdx.x * 256 + threadIdx.x;
    const int stride = gridDim.x * 256;
    float s = 0.0f, sq = 0.0f;
    for (int i = tid; i < N_OUT * COUT; i += stride) {
        const float x = out[i]; s += x; sq += x * x;
    }
    __shared__ float ls[256], lsq[256];
    ls[threadIdx.x] = s; lsq[threadIdx.x] = sq;
    __syncthreads();
    if (threadIdx.x < 64) {
        const int c = threadIdx.x;
        atomicAdd(&stats[c],      ls[c] + ls[c+64] + ls[c+128] + ls[c+192]);
        atomicAdd(&stats[64 + c], lsq[c] + lsq[c+64] + lsq[c+128] + lsq[c+192]);
    }
}

__global__ __launch_bounds__(256) void bn_norm_fb(
    float* __restrict__ out, const float* __restrict__ stats,
    const float* __restrict__ gamma, const float* __restrict__ beta)
{
    __shared__ float scale[COUT], bias[COUT];
    if (threadIdx.x < COUT) {
        const int c = threadIdx.x;
        const float invN = 1.0f / (float)N_OUT;
        const float mean = stats[c] * invN;
        const float var  = stats[64 + c] * invN - mean * mean;
        const float inv  = rsqrtf(var + BN_EPS);
        const float g    = gamma[c];
        scale[c] = inv * g;
        bias[c]  = beta[c] - mean * inv * g;
    }
    __syncthreads();
    const int tid    = blockIdx.x * blockDim.x + threadIdx.x;
    const int stride = gridDim.x * blockDim.x;
    float4* o4 = (float4*)out;
    for (int i = tid; i < N_OUT * COUT / 4; i += stride) {
        float4 v = o4[i];
        const int c0 = (i * 4) & 63;
        v.x = v.x * scale[c0 + 0] + bias[c0 + 0];
        v.y = v.y * scale[c0 + 1] + bias[c0 + 1];
        v.z = v.z * scale[c0 + 2] + bias[c0 + 2];
        v.w = v.w * scale[c0 + 3] + bias[c0 + 3];
        o4[i] = v;
    }
}

extern "C" void kernel_launch(void* const* d_in, const int* in_sizes, int n_in,
                              void* d_out, int out_size, void* d_ws, size_t ws_size,
                              hipStream_t stream) {
    const float* data    = (const float*)d_in[0];
    const float* W       = (const float*)d_in[1];
    const float* gamma   = (const float*)d_in[2];
    const float* beta    = (const float*)d_in[3];
    const int*   in_idx  = (const int*)d_in[4];
    const int*   out_idx = (const int*)d_in[5];
    float* out = (float*)d_out;

    // workspace: bf16 accumulation buffer (50.3 MB) + stats
    u32*   outbf = (u32*)d_ws;                   // N_OUT*32 packed pairs
    float* stats = (float*)(outbf + (size_t)N_OUT * 32);
    const size_t needed = (size_t)N_OUT * 32 * 4 + 128 * 4;

    if (ws_size >= needed) {
        hipMemsetAsync(outbf, 0, (size_t)N_OUT * 32 * sizeof(u32), stream);
        hipMemsetAsync(stats, 0, 128 * sizeof(float), stream);

        conv_scatter_pk<<<KK * BPK, CONV_BLOCK, 0, stream>>>(
            data, W, in_idx, out_idx, outbf);
        bn_stats_bf<<<1024, 256, 0, stream>>>(outbf, stats);
        bn_norm_bf<<<2048, 256, 0, stream>>>(outbf, stats, gamma, beta, out);
    } else {
        float* stats_fb = (float*)d_ws;          // 512 B
        hipMemsetAsync(d_out, 0, (size_t)N_OUT * COUT * sizeof(float), stream);
        hipMemsetAsync(stats_fb, 0, 128 * sizeof(float), stream);
        conv_scatter_fb<<<KK * BPK, CONV_BLOCK, 0, stream>>>(
            data, W, in_idx, out_idx, out);
        bn_stats_fb<<<1024, 256, 0, stream>>>(out, stats_fb);
        bn_norm_fb<<<2048, 256, 0, stream>>>(out, stats_fb, gamma, beta);
    }
}